// Round 2
// baseline (1975.047 us; speedup 1.0000x reference)
//
#include <hip/hip_runtime.h>
#include <math.h>

#define LSEQ   2048
#define DMODEL 512
#define NHEAD  8
#define DK     64
#define UK     38            // u = int(5*ln(2048)) = 38

// order-preserving map double -> u64 (monotone: x<y  <=>  map(x)<map(y))
__device__ __forceinline__ unsigned long long mapu64(double x){
    unsigned long long s = (unsigned long long)__double_as_longlong(x);
    return (s & 0x8000000000000000ull) ? ~s : (s | 0x8000000000000000ull);
}
__device__ __forceinline__ double unmapu64(unsigned long long u){
    long long s = (u & 0x8000000000000000ull) ? (long long)(u ^ 0x8000000000000000ull)
                                              : (long long)(~u);
    return __longlong_as_double(s);
}

// ---------------- Q/K projection, f64 accumulation (exact from f32 inputs) ---------
__global__ __launch_bounds__(256) void gemm_qk_f64(
    const float* __restrict__ X, const float* __restrict__ Wq,
    const float* __restrict__ Wk, const float* __restrict__ bq,
    const float* __restrict__ bk, double* __restrict__ qD, double* __restrict__ ktD)
{
    const int mode = blockIdx.z;                 // 0 = Q, 1 = K
    const float* __restrict__ W    = mode ? Wk : Wq;
    const float* __restrict__ bias = mode ? bk : bq;
    const int r0 = blockIdx.x * 64, c0 = blockIdx.y * 64;
    __shared__ float Xs[32][68];
    __shared__ float Ws[32][68];
    const int tid = threadIdx.x;
    const int tx = tid & 15, ty = tid >> 4;
    double acc[4][4] = {};
    for (int kb = 0; kb < DMODEL; kb += 32){
        __syncthreads();
        #pragma unroll
        for (int i = 0; i < 2; ++i){
            int f4 = i * 256 + tid;
            int m = f4 >> 3, kg = (f4 & 7) << 2;
            float4 xv = *(const float4*)&X[(r0 + m) * DMODEL + kb + kg];
            Xs[kg+0][m] = xv.x; Xs[kg+1][m] = xv.y; Xs[kg+2][m] = xv.z; Xs[kg+3][m] = xv.w;
            float4 wv = *(const float4*)&W[(c0 + m) * DMODEL + kb + kg];
            Ws[kg+0][m] = wv.x; Ws[kg+1][m] = wv.y; Ws[kg+2][m] = wv.z; Ws[kg+3][m] = wv.w;
        }
        __syncthreads();
        #pragma unroll
        for (int kk = 0; kk < 32; ++kk){
            float4 av = *(const float4*)&Xs[kk][ty << 2];
            float4 bv = *(const float4*)&Ws[kk][tx << 2];
            double a[4] = {(double)av.x, (double)av.y, (double)av.z, (double)av.w};
            double b[4] = {(double)bv.x, (double)bv.y, (double)bv.z, (double)bv.w};
            #pragma unroll
            for (int ii = 0; ii < 4; ++ii)
                #pragma unroll
                for (int jj = 0; jj < 4; ++jj)
                    acc[ii][jj] = fma(a[ii], b[jj], acc[ii][jj]);
        }
    }
    #pragma unroll
    for (int ii = 0; ii < 4; ++ii){
        int r = r0 + (ty << 2) + ii;
        int bidx = r >> 11, l = r & 2047;
        int h = c0 >> 6;
        int bh = bidx * NHEAD + h;
        #pragma unroll
        for (int jj = 0; jj < 4; ++jj){
            int dk = (tx << 2) + jj;
            double v = acc[ii][jj] + (double)bias[c0 + dk];
            if (mode == 0){
                // fold 1/sqrt(Dk)=1/8 into Q: exact power-of-2 scaling
                qD[((size_t)bh * LSEQ + l) * DK + dk] = v * 0.125;
            } else {
                // K transposed per (b,h): [bh][dk][l]
                ktD[(size_t)bh * (DK * LSEQ) + (size_t)dk * LSEQ + l] = v;
            }
        }
    }
}

// ---------------- f32 GEMM: V projection (mode 0) and O projection (mode 1) -------
__global__ __launch_bounds__(256) void gemm_f32(
    const float* __restrict__ X, const float* __restrict__ W,
    const float* __restrict__ bias, float* __restrict__ out, const int mode)
{
    const int r0 = blockIdx.x * 64, c0 = blockIdx.y * 64;
    __shared__ float Xs[32][68];
    __shared__ float Ws[32][68];
    const int tid = threadIdx.x;
    const int tx = tid & 15, ty = tid >> 4;
    float acc[4][4] = {};
    for (int kb = 0; kb < DMODEL; kb += 32){
        __syncthreads();
        #pragma unroll
        for (int i = 0; i < 2; ++i){
            int f4 = i * 256 + tid;
            int m = f4 >> 3, kg = (f4 & 7) << 2;
            float4 xv = *(const float4*)&X[(r0 + m) * DMODEL + kb + kg];
            Xs[kg+0][m] = xv.x; Xs[kg+1][m] = xv.y; Xs[kg+2][m] = xv.z; Xs[kg+3][m] = xv.w;
            float4 wv = *(const float4*)&W[(c0 + m) * DMODEL + kb + kg];
            Ws[kg+0][m] = wv.x; Ws[kg+1][m] = wv.y; Ws[kg+2][m] = wv.z; Ws[kg+3][m] = wv.w;
        }
        __syncthreads();
        #pragma unroll
        for (int kk = 0; kk < 32; ++kk){
            float4 av = *(const float4*)&Xs[kk][ty << 2];
            float4 bv = *(const float4*)&Ws[kk][tx << 2];
            float a[4] = {av.x, av.y, av.z, av.w};
            float b[4] = {bv.x, bv.y, bv.z, bv.w};
            #pragma unroll
            for (int ii = 0; ii < 4; ++ii)
                #pragma unroll
                for (int jj = 0; jj < 4; ++jj)
                    acc[ii][jj] = fmaf(a[ii], b[jj], acc[ii][jj]);
        }
    }
    #pragma unroll
    for (int ii = 0; ii < 4; ++ii){
        int r = r0 + (ty << 2) + ii;
        float4 o;
        o.x = acc[ii][0] + bias[c0 + (tx << 2) + 0];
        o.y = acc[ii][1] + bias[c0 + (tx << 2) + 1];
        o.z = acc[ii][2] + bias[c0 + (tx << 2) + 2];
        o.w = acc[ii][3] + bias[c0 + (tx << 2) + 3];
        if (mode == 0){
            int bidx = r >> 11, l = r & 2047, h = c0 >> 6;
            *(float4*)&out[((size_t)(bidx * NHEAD + h) * LSEQ + l) * DK + (tx << 2)] = o;
        } else {
            *(float4*)&out[(size_t)r * DMODEL + c0 + (tx << 2)] = o;
        }
    }
}

// ---- attention: one wave per query row; all 2048 exact f64 scores in registers ----
// Exact 38th-largest per row via 64-step bitwise binary search on monotone u64 keys.
__global__ __launch_bounds__(256) void attn_kernel(
    const double* __restrict__ qD, const double* __restrict__ ktD,
    const float* __restrict__ vbuf, float* __restrict__ ctx)
{
    __shared__ double Kld[DK * 64];      // 32 KB: [d][j] chunk of 64 keys
    __shared__ double qs[4][DK];         // the block's 4 query rows (pre-scaled)
    __shared__ double wls[4][64];        // selected scores -> softmax weights
    __shared__ int    jls[4][64];        // selected key indices

    const int tid  = threadIdx.x;
    const int lane = tid & 63;
    const int wv   = tid >> 6;           // wave wv owns query row l0+wv
    const int bh   = blockIdx.x >> 9;    // 512 row-blocks per (b,h)
    const int l0   = (blockIdx.x & 511) << 2;
    const size_t ktBase = (size_t)bh * (DK * LSEQ);

    // stage the 4 q rows (one element per thread)
    qs[tid >> 6][tid & 63] = qD[((size_t)bh * LSEQ + l0 + (tid >> 6)) * DK + (tid & 63)];

    unsigned long long u[32];            // this lane's 32 scores as monotone u64 keys

    #pragma unroll
    for (int ch = 0; ch < 32; ++ch){
        const int cb = ch << 6;
        __syncthreads();                 // q staged / prev chunk's reads done
        #pragma unroll
        for (int i = 0; i < 8; ++i){     // stage 64 keys x 64 dims (f64)
            int flat = (i * 256 + tid) << 1;
            int d = flat >> 6, jj = flat & 63;
            *(double2*)&Kld[flat] = *(const double2*)&ktD[ktBase + (size_t)d * LSEQ + cb + jj];
        }
        __syncthreads();
        double a = 0.0;
        #pragma unroll 8
        for (int d = 0; d < DK; d += 2){
            double2 qq = *(const double2*)&qs[wv][d];     // same-address broadcast
            a = fma(qq.x, Kld[(d << 6) + lane], a);
            a = fma(qq.y, Kld[((d + 1) << 6) + lane], a);
        }
        u[ch] = mapu64(a);               // score of key cb+lane for row l0+wv
    }

    // exact 38th-largest key T: max T with count(u >= T) >= 38
    unsigned long long T = 0ull;
    for (int bit = 63; bit >= 0; --bit){
        unsigned long long Tp = T | (1ull << bit);
        int c = 0;
        #pragma unroll
        for (int ch = 0; ch < 32; ++ch) c += (u[ch] >= Tp) ? 1 : 0;
        #pragma unroll
        for (int off = 32; off; off >>= 1) c += __shfl_xor(c, off);
        if (c >= UK) T = Tp;
    }

    // compact selected (u >= T: ties kept, matching reference mask) into LDS list
    const unsigned long long mlt = (1ull << lane) - 1ull;
    int base = 0;
    #pragma unroll
    for (int ch = 0; ch < 32; ++ch){
        bool sel = (u[ch] >= T);
        unsigned long long bm = __ballot(sel);
        int p = base + __popcll(bm & mlt);
        if (sel && p < 64){
            wls[wv][p] = unmapu64(u[ch]);
            jls[wv][p] = (ch << 6) + lane;
        }
        base += __popcll(bm);
    }
    int cnt = base > 64 ? 64 : base;     // = 38 in practice (ties measure-zero)

    // softmax over selected (masked entries underflow to exactly 0 in the reference)
    bool va = lane < cnt;
    double x = va ? wls[wv][lane] : -1.0e308;
    double mv = x;
    #pragma unroll
    for (int off = 32; off; off >>= 1) mv = fmax(mv, __shfl_xor(mv, off));
    double w = va ? exp(x - mv) : 0.0;
    double zs = w;
    #pragma unroll
    for (int off = 32; off; off >>= 1) zs += __shfl_xor(zs, off);
    if (va) wls[wv][lane] = w;
    double invZ = 1.0 / zs;

    // sparse AV: ~38 coalesced V-row gathers (lane = dim)
    const float* __restrict__ vsl = vbuf + (size_t)bh * (LSEQ * DK);
    double o = 0.0;
    for (int e = 0; e < cnt; ++e){
        double ww = wls[wv][e];          // wave-uniform broadcast
        int j = jls[wv][e];
        o = fma(ww, (double)vsl[(size_t)j * DK + lane], o);
    }
    int l = l0 + wv;
    int b = bh >> 3, h = bh & 7;
    ctx[((size_t)b * LSEQ + l) * DMODEL + h * DK + lane] = (float)(o * invZ);
}

extern "C" void kernel_launch(void* const* d_in, const int* in_sizes, int n_in,
                              void* d_out, int out_size, void* d_ws, size_t ws_size,
                              hipStream_t stream)
{
    const float* x  = (const float*)d_in[0];
    const float* Wq = (const float*)d_in[1];
    const float* bq = (const float*)d_in[2];
    const float* Wk = (const float*)d_in[3];
    const float* bk = (const float*)d_in[4];
    const float* Wv = (const float*)d_in[5];
    const float* bv = (const float*)d_in[6];
    const float* Wo = (const float*)d_in[7];
    const float* bo = (const float*)d_in[8];
    float* out = (float*)d_out;
    char* ws = (char*)d_ws;
    // workspace: qD 16MB | ktD 16MB | V 8MB | ctx 8MB  (48MB total)
    double* qD  = (double*)(ws);
    double* ktD = (double*)(ws + (size_t)16 * 1024 * 1024);
    float*  vB  = (float*) (ws + (size_t)32 * 1024 * 1024);
    float*  ctx = (float*) (ws + (size_t)40 * 1024 * 1024);

    dim3 blk(256);
    gemm_qk_f64<<<dim3(64, 8, 2), blk, 0, stream>>>(x, Wq, Wk, bq, bk, qD, ktD);
    gemm_f32  <<<dim3(64, 8),    blk, 0, stream>>>(x, Wv, bv, vB, 0);
    attn_kernel<<<dim3(16 * 512), blk, 0, stream>>>(qD, ktD, vB, ctx);
    gemm_f32  <<<dim3(64, 8),    blk, 0, stream>>>(ctx, Wo, bo, out, 1);
}